// Round 10
// baseline (1277.898 us; speedup 1.0000x reference)
//
#include <hip/hip_runtime.h>

typedef _Float16 half8 __attribute__((ext_vector_type(8)));
typedef float    float4v __attribute__((ext_vector_type(4)));
typedef unsigned int u32;

#define NQ 8
#define KCODES 4096
#define DIMS 128
#define BATCH 8
#define SEQ 4096
#define ROWS (BATCH*SEQ)            // 32768
#define TM 64                       // rows per block
#define NBLK (ROWS/TM)              // 512 = 2 blocks/CU
#define RESPAD 132                  // res row stride (floats)
#define CANDROW 67                  // cand row stride (uints)
#define OUT_ELEMS (BATCH*DIMS*SEQ)  // 4194304
#define IDX_ELEMS (BATCH*SEQ*NQ)    // 262144
#define LOSS_DIV (1.0f/33554432.0f) // 1/(Q*B*N*D)
#define FRAGQ ((size_t)4*256*64*8)  // halves per q-stage of bhi (1 MB)
#define SBIAS 384.0f                // key bias: keys = dot - csq/2 + 384, ~[240,450] > 0
#define WIN 2.0f                    // refine window (>> f16 errs + pack trunc)

__device__ __forceinline__ unsigned umax_(unsigned a, unsigned b){ return a>b?a:b; }
__device__ __forceinline__ unsigned umin_(unsigned a, unsigned b){ return a<b?a:b; }

__device__ __forceinline__ void gload16(const void* g, void* l) {
    __builtin_amdgcn_global_load_lds(
        (const __attribute__((address_space(1))) u32*)g,
        (__attribute__((address_space(3))) u32*)l, 16, 0, 0);
}

// asm-pinned B loads: "=v" outputs pin the dest regs (regalloc can't collapse)
#define B_ISSUE(X0,X1,X2,X3,OFF)                                              \
    asm volatile("global_load_dwordx4 %0, %4, %8 offset:" #OFF "\n\t"         \
                 "global_load_dwordx4 %1, %5, %8 offset:" #OFF "\n\t"         \
                 "global_load_dwordx4 %2, %6, %8 offset:" #OFF "\n\t"         \
                 "global_load_dwordx4 %3, %7, %8 offset:" #OFF                \
                 : "=v"(X0), "=v"(X1), "=v"(X2), "=v"(X3)                     \
                 : "v"(vo0), "v"(vo1), "v"(vo2), "v"(vo3), "s"(bq))

// counted wait: set issued 3 tiles ago has landed. "+v" deps order it.
#define B_WAIT(X0,X1,X2,X3)                                                   \
    asm volatile("s_waitcnt vmcnt(8)"                                         \
                 : "+v"(X0), "+v"(X1), "+v"(X2), "+v"(X3))

// ---------------- prep: csq f32 ; cinit_h = f16(384 - csq/2) ----------------
__global__ void prep_csq(const float* __restrict__ cb, float* __restrict__ csq,
                         _Float16* __restrict__ cinit_h) {
    int c = blockIdx.x * 256 + threadIdx.x;
    const float4* p = (const float4*)(cb + (size_t)c * DIMS);
    float s = 0.f;
#pragma unroll
    for (int i = 0; i < 32; ++i) {
        float4 v = p[i];
        s += v.x * v.x + v.y * v.y + v.z * v.z + v.w * v.w;
    }
    csq[c] = s;
    cinit_h[c] = (_Float16)(SBIAS - 0.5f * s);
}

// ---------------- prep: codebook -> f16 MFMA B-fragments ----------------
__global__ void prep_frags(const float* __restrict__ cb, _Float16* __restrict__ bhi,
                           float* __restrict__ loss_accum) {
    int g = blockIdx.x * 256 + threadIdx.x;
    if (g == 0) loss_accum[0] = 0.f;
    int lane = g & 63;
    int nt   = (g >> 6) & 255;
    int kb   = (g >> 14) & 3;
    int q    = g >> 16;
    int code = nt * 16 + (lane & 15);
    int k0   = kb * 32 + ((lane >> 4) * 8);
    const float* src = cb + ((size_t)q * KCODES + code) * DIMS + k0;
    float4 v0 = *(const float4*)(src);
    float4 v1 = *(const float4*)(src + 4);
    half8 h;
    h[0] = (_Float16)v0.x; h[1] = (_Float16)v0.y; h[2] = (_Float16)v0.z; h[3] = (_Float16)v0.w;
    h[4] = (_Float16)v1.x; h[5] = (_Float16)v1.y; h[6] = (_Float16)v1.z; h[7] = (_Float16)v1.w;
    *(half8*)(bhi + (size_t)g * 8) = h;
}

// 16 MFMA + insert. MODE>=2: insert stubbed to 1 XOR/key (keeps acc+p1 live).
template<int MODE>
__device__ __forceinline__ void compute16(
        const half8& b0, const half8& b1, const half8& b2, const half8& b3,
        float csv, unsigned idxv, const half8 (&ahi)[4][4],
        unsigned (&p1)[4][4], unsigned (&p2)[4][4]) {
    float4v acc[4];
#pragma unroll
    for (int mt = 0; mt < 4; ++mt) { acc[mt][0]=csv; acc[mt][1]=csv; acc[mt][2]=csv; acc[mt][3]=csv; }
    __builtin_amdgcn_s_setprio(1);
#pragma unroll
    for (int mt = 0; mt < 4; ++mt) acc[mt] = __builtin_amdgcn_mfma_f32_16x16x32_f16(ahi[mt][0], b0, acc[mt], 0, 0, 0);
#pragma unroll
    for (int mt = 0; mt < 4; ++mt) acc[mt] = __builtin_amdgcn_mfma_f32_16x16x32_f16(ahi[mt][1], b1, acc[mt], 0, 0, 0);
#pragma unroll
    for (int mt = 0; mt < 4; ++mt) acc[mt] = __builtin_amdgcn_mfma_f32_16x16x32_f16(ahi[mt][2], b2, acc[mt], 0, 0, 0);
#pragma unroll
    for (int mt = 0; mt < 4; ++mt) acc[mt] = __builtin_amdgcn_mfma_f32_16x16x32_f16(ahi[mt][3], b3, acc[mt], 0, 0, 0);
    __builtin_amdgcn_s_setprio(0);
#pragma unroll
    for (int mt = 0; mt < 4; ++mt)
#pragma unroll
        for (int r = 0; r < 4; ++r) {
            if constexpr (MODE >= 2) {
                p1[mt][r] ^= __float_as_uint(acc[mt][r]);   // stub: keep acc live
            } else {
                unsigned p    = (__float_as_uint(acc[mt][r]) & 0xFFFFF000u) | idxv;
                unsigned old1 = p1[mt][r];
                p1[mt][r] = umax_(old1, p);
                p2[mt][r] = umax_(umin_(old1, p), p2[mt][r]);   // med3-fusable
            }
        }
}

// MODE 0: real kernel (writes out/loss). MODE 1: refine stubbed (no exact-dot
// gathers). MODE 2: + insert stubbed. MODE 3: + B_WAIT removed (issue floor).
// MODE>0 write NOTHING global; asm sinks prevent DCE (rule #17).
template<int MODE>
__launch_bounds__(256, 2)
__global__ void rvq_main(const float* __restrict__ x, const float* __restrict__ cb,
                         const _Float16* __restrict__ bhi,
                         const float* __restrict__ csq, const _Float16* __restrict__ cinit_h,
                         float* __restrict__ out, float* __restrict__ loss_accum) {
    __shared__ float    res[TM][RESPAD];
    __shared__ __align__(16) _Float16 cinq_lds[KCODES];
    __shared__ unsigned cand[TM][CANDROW];
    __shared__ float    fbin[TM];
    __shared__ float    red[256];

    int tid  = threadIdx.x;
    int lane = tid & 63;
    int wv   = tid >> 6;
    int col  = lane & 15;
    int r0   = blockIdx.x * TM;
    int b    = r0 >> 12;
    int n0   = r0 & (SEQ - 1);
    const float* xb = x + (size_t)b * DIMS * SEQ + n0;

    {
        int d = tid >> 1, half = (tid & 1) * 32;
        const float* src = xb + (size_t)d * SEQ + half;
#pragma unroll
        for (int t4 = 0; t4 < 8; ++t4) {
            float4 v = *(const float4*)(src + t4 * 4);
            res[half + t4 * 4 + 0][d] = v.x;
            res[half + t4 * 4 + 1][d] = v.y;
            res[half + t4 * 4 + 2][d] = v.z;
            res[half + t4 * 4 + 3][d] = v.w;
        }
    }

    float lossacc = 0.f;
    int ntBase = wv * 64;

    for (int q = 0; q < NQ; ++q) {
        asm volatile("s_waitcnt lgkmcnt(0)" ::: "memory");
        __builtin_amdgcn_s_barrier();

        const _Float16* bq   = bhi + (size_t)q * FRAGQ;
        const _Float16* cq   = cinit_h + q * KCODES;
        const float*    csqq = csq + q * KCODES;

        {
            const _Float16* g0 = cq + wv * 1024 + lane * 8;
            gload16(g0,       (char*)cinq_lds + wv * 2048);
            gload16(g0 + 512, (char*)cinq_lds + wv * 2048 + 1024);
        }

        u32 vo0, vo1, vo2, vo3;
        {
            u32 base = (u32)(((ntBase + 3) * 64 + lane) << 4);
            vo0 = base;
            vo1 = base + (256u * 64u * 16u);
            vo2 = base + (512u * 64u * 16u);
            vo3 = base + (768u * 64u * 16u);
        }
        half8 a0,a1,a2,a3, b0,b1,b2,b3, c0,c1,c2,c3, d0,d1,d2,d3;
        B_ISSUE(a0,a1,a2,a3, -3072);
        B_ISSUE(b0,b1,b2,b3, -2048);
        B_ISSUE(c0,c1,c2,c3, -1024);
        // outstanding: cinq(2) + 12 = 14

        half8 ahi[4][4];
#pragma unroll
        for (int mt = 0; mt < 4; ++mt)
#pragma unroll
        for (int kb = 0; kb < 4; ++kb) {
            int row = mt * 16 + col;
            int k0  = kb * 32 + (lane >> 4) * 8;
            float4 v0 = *(const float4*)&res[row][k0];
            float4 v1 = *(const float4*)&res[row][k0 + 4];
            half8 h;
            h[0] = (_Float16)v0.x; h[1] = (_Float16)v0.y; h[2] = (_Float16)v0.z; h[3] = (_Float16)v0.w;
            h[4] = (_Float16)v1.x; h[5] = (_Float16)v1.y; h[6] = (_Float16)v1.z; h[7] = (_Float16)v1.w;
            ahi[mt][kb] = h;
        }
        // RACE FIX (new this round): guarantee cinq DMA landed before cs reads
        asm volatile("s_waitcnt vmcnt(12)" ::: "memory");

        unsigned p1[4][4], p2[4][4];
#pragma unroll
        for (int mt = 0; mt < 4; ++mt)
#pragma unroll
        for (int r = 0; r < 4; ++r) { p1[mt][r] = 0u; p2[mt][r] = 0u; }

        unsigned idx0 = (unsigned)(ntBase * 16 + col);

        for (int ii = 0; ii < 16; ++ii) {
            int t = ii * 4;
            float cs0 = (float)cinq_lds[(ntBase + t + 0) * 16 + col];
            float cs1 = (float)cinq_lds[(ntBase + t + 1) * 16 + col];
            float cs2 = (float)cinq_lds[(ntBase + t + 2) * 16 + col];
            float cs3 = (float)cinq_lds[(ntBase + t + 3) * 16 + col];

            if constexpr (MODE < 3) B_WAIT(a0,a1,a2,a3);
            B_ISSUE(d0,d1,d2,d3, 0);
            compute16<MODE>(a0,a1,a2,a3, cs0, idx0 + (unsigned)(t+0)*16u, ahi, p1, p2);

            if constexpr (MODE < 3) B_WAIT(b0,b1,b2,b3);
            B_ISSUE(a0,a1,a2,a3, 1024);
            compute16<MODE>(b0,b1,b2,b3, cs1, idx0 + (unsigned)(t+1)*16u, ahi, p1, p2);

            if constexpr (MODE < 3) B_WAIT(c0,c1,c2,c3);
            B_ISSUE(b0,b1,b2,b3, 2048);
            compute16<MODE>(c0,c1,c2,c3, cs2, idx0 + (unsigned)(t+2)*16u, ahi, p1, p2);

            if constexpr (MODE < 3) B_WAIT(d0,d1,d2,d3);
            B_ISSUE(c0,c1,c2,c3, 3072);
            compute16<MODE>(d0,d1,d2,d3, cs3, idx0 + (unsigned)(t+3)*16u, ahi, p1, p2);

            vo0 += 4096; vo1 += 4096; vo2 += 4096; vo3 += 4096;
        }
        __syncthreads();   // drains tail prefetches (vmcnt 0)

        // pair-merge best-2 across (lane, lane^1) -> top-2-of-128 slices
#pragma unroll
        for (int mt = 0; mt < 4; ++mt)
#pragma unroll
        for (int r = 0; r < 4; ++r) {
            unsigned q1 = p1[mt][r], q2 = p2[mt][r];
            unsigned o1 = (unsigned)__shfl_xor((int)q1, 1, 64);
            unsigned o2 = (unsigned)__shfl_xor((int)q2, 1, 64);
            unsigned n1 = umax_(q1, o1);
            unsigned n2 = umax_(umin_(q1, o1), umax_(q2, o2));
            if ((lane & 1) == 0) {
                int row = mt * 16 + (lane >> 4) * 4 + r;
                int cc  = wv * 16 + (col >> 1) * 2;
                cand[row][cc]     = n1;
                cand[row][cc + 1] = n2;
            }
        }
        __syncthreads();

        if constexpr (MODE == 0) {
            // exact f32 refine
            int row = tid >> 2, s = tid & 3;
            const unsigned* cp = &cand[row][s * 16];
            unsigned m = 0;
#pragma unroll
            for (int k = 0; k < 16; ++k) m = umax_(m, cp[k]);
            m = umax_(m, (unsigned)__shfl_xor((int)m, 1, 64));
            m = umax_(m, (unsigned)__shfl_xor((int)m, 2, 64));
            float thr = __uint_as_float(m) - WIN;
            float bk = -3.4e38f;
            int   bi = KCODES;
            const float4* rv = (const float4*)&res[row][0];
            for (int k = 0; k < 16; ++k) {
                unsigned e = cp[k];
                if (__uint_as_float(e) >= thr) {
                    int idx = (int)(e & 0xFFFu);
                    const float4* cv = (const float4*)(cb + ((size_t)q * KCODES + idx) * DIMS);
                    float acc = 0.f;
#pragma unroll
                    for (int jj = 0; jj < 32; ++jj) {
                        float4 c4 = cv[jj];
                        float4 r4 = rv[jj];
                        acc = fmaf(r4.x, c4.x, acc);
                        acc = fmaf(r4.y, c4.y, acc);
                        acc = fmaf(r4.z, c4.z, acc);
                        acc = fmaf(r4.w, c4.w, acc);
                    }
                    float key = acc - 0.5f * csqq[idx];
                    if (key > bk || (key == bk && idx < bi)) { bk = key; bi = idx; }
                }
            }
#pragma unroll
            for (int mask = 1; mask <= 2; mask <<= 1) {
                float ok = __shfl_xor(bk, mask, 64);
                int   oi = __shfl_xor(bi, mask, 64);
                if (ok > bk || (ok == bk && oi < bi)) { bk = ok; bi = oi; }
            }
            if (s == 0) {
                fbin[row] = (float)bi;
                out[OUT_ELEMS + (size_t)(r0 + row) * NQ + q] = (float)bi;
            }
        } else {
            // refine stub: packed best-1 (no exact-dot gathers, no out writes)
            int row = tid >> 2, s = tid & 3;
            const unsigned* cp = &cand[row][s * 16];
            unsigned m = 0;
#pragma unroll
            for (int k = 0; k < 16; ++k) m = umax_(m, cp[k]);
            m = umax_(m, (unsigned)__shfl_xor((int)m, 1, 64));
            m = umax_(m, (unsigned)__shfl_xor((int)m, 2, 64));
            if (s == 0) fbin[row] = (float)(m & 0xFFFu);
        }
        __syncthreads();

        // residual update + commitment loss (all modes; index always in-range)
        {
            int row = tid >> 2, j = tid & 3;
            int bi = (int)fbin[row];
            const float* cv = cb + ((size_t)q * KCODES + bi) * DIMS + j * 32;
            float* rp = &res[row][j * 32];
#pragma unroll
            for (int t = 0; t < 8; ++t) {
                float4 c4 = *(const float4*)(cv + t * 4);
                float4 r4 = *(const float4*)(rp + t * 4);
                r4.x -= c4.x; lossacc = fmaf(r4.x, r4.x, lossacc);
                r4.y -= c4.y; lossacc = fmaf(r4.y, r4.y, lossacc);
                r4.z -= c4.z; lossacc = fmaf(r4.z, r4.z, lossacc);
                r4.w -= c4.w; lossacc = fmaf(r4.w, r4.w, lossacc);
                *(float4*)(rp + t * 4) = r4;
            }
        }
    }

    __syncthreads();
    if constexpr (MODE == 0) {
        red[tid] = lossacc;
        __syncthreads();
        for (int s = 128; s > 0; s >>= 1) {
            if (tid < s) red[tid] += red[tid + s];
            __syncthreads();
        }
        if (tid == 0) atomicAdd(loss_accum, red[0]);

        int d = tid >> 1, half = (tid & 1) * 32;
        const float* src = xb + (size_t)d * SEQ + half;
        float* dst = out + (size_t)b * DIMS * SEQ + (size_t)d * SEQ + n0 + half;
#pragma unroll
        for (int t4 = 0; t4 < 8; ++t4) {
            float4 v = *(const float4*)(src + t4 * 4);
            v.x -= res[half + t4 * 4 + 0][d];
            v.y -= res[half + t4 * 4 + 1][d];
            v.z -= res[half + t4 * 4 + 2][d];
            v.w -= res[half + t4 * 4 + 3][d];
            *(float4*)(dst + t4 * 4) = v;
        }
    } else {
        // DCE guards: keep the whole computation live without global writes
        float t = lossacc + fbin[lane] + red[0];
        asm volatile("" :: "v"(t));
    }
}

__global__ void finish_loss(const float* __restrict__ loss_accum, float* __restrict__ out) {
    out[OUT_ELEMS + IDX_ELEMS] = loss_accum[0] * LOSS_DIV;
}

extern "C" void kernel_launch(void* const* d_in, const int* in_sizes, int n_in,
                              void* d_out, int out_size, void* d_ws, size_t ws_size,
                              hipStream_t stream) {
    const float* x  = (const float*)d_in[0];
    const float* cb = (const float*)d_in[1];
    float* out = (float*)d_out;
    char*  ws  = (char*)d_ws;

    float*     loss_accum = (float*)ws;
    float*     csq     = (float*)(ws + 256);                       // 131072 B
    _Float16*  cinit_h = (_Float16*)(ws + 256 + 131072);           // 65536 B
    _Float16*  bhi     = (_Float16*)(ws + 256 + 131072 + 65536);   // 8 MB (+16KB
                                 // tail pad: prefetch overreach lands here)

    hipLaunchKernelGGL(prep_csq,   dim3(128),  dim3(256), 0, stream, cb, csq, cinit_h);
    hipLaunchKernelGGL(prep_frags, dim3(2048), dim3(256), 0, stream, cb, bhi, loss_accum);
    // ABLATION LADDER (timing-only dispatches; no global side effects):
    hipLaunchKernelGGL(rvq_main<3>, dim3(NBLK), dim3(256), 0, stream,
                       x, cb, bhi, csq, cinit_h, out, loss_accum);  // issue floor
    hipLaunchKernelGGL(rvq_main<2>, dim3(NBLK), dim3(256), 0, stream,
                       x, cb, bhi, csq, cinit_h, out, loss_accum);  // + wait stalls
    hipLaunchKernelGGL(rvq_main<1>, dim3(NBLK), dim3(256), 0, stream,
                       x, cb, bhi, csq, cinit_h, out, loss_accum);  // + insert VALU
    // REAL kernel (round-9 structure + cinq race fix):
    hipLaunchKernelGGL(rvq_main<0>, dim3(NBLK), dim3(256), 0, stream,
                       x, cb, bhi, csq, cinit_h, out, loss_accum);
    hipLaunchKernelGGL(finish_loss, dim3(1), dim3(1), 0, stream, loss_accum, out);
}

// Round 12
// 751.081 us; speedup vs baseline: 1.7014x; 1.7014x over previous
//
#include <hip/hip_runtime.h>

typedef _Float16 half8 __attribute__((ext_vector_type(8)));
typedef float    float4v __attribute__((ext_vector_type(4)));
typedef unsigned int u32;

#define NQ 8
#define KCODES 4096
#define DIMS 128
#define BATCH 8
#define SEQ 4096
#define ROWS (BATCH*SEQ)            // 32768
#define TM 64                       // rows per block
#define NBLK (ROWS/TM)              // 512 blocks = 2 blocks/CU
#define NTHREADS 512                // 8 waves -> 16 waves/CU = 4/SIMD
#define RESPAD 132                  // res row stride (floats)
#define CANDROW 97                  // 96 entries (32 slices x best-3) + pad
#define OUT_ELEMS (BATCH*DIMS*SEQ)  // 4194304
#define IDX_ELEMS (BATCH*SEQ*NQ)    // 262144
#define LOSS_DIV (1.0f/33554432.0f) // 1/(Q*B*N*D)
#define FRAGQ ((size_t)4*256*64*8)  // halves per q-stage of bhi (1 MB)
#define SBIAS 384.0f                // key bias: keys = dot - csq/2 + 384 > 0
#define WIN 2.0f                    // refine window (>> f16/pack noise ~0.27)

__device__ __forceinline__ unsigned umax_(unsigned a, unsigned b){ return a>b?a:b; }

// async global->LDS DMA, 16 B/lane; LDS dest = wave-uniform base + lane*16
__device__ __forceinline__ void gload16(const void* g, void* l) {
    __builtin_amdgcn_global_load_lds(
        (const __attribute__((address_space(1))) u32*)g,
        (__attribute__((address_space(3))) u32*)l, 16, 0, 0);
}

// ---------------- prep: csq f32 ; cinit_h = f16(384 - csq/2) ----------------
__global__ void prep_csq(const float* __restrict__ cb, float* __restrict__ csq,
                         _Float16* __restrict__ cinit_h) {
    int c = blockIdx.x * 256 + threadIdx.x;
    const float4* p = (const float4*)(cb + (size_t)c * DIMS);
    float s = 0.f;
#pragma unroll
    for (int i = 0; i < 32; ++i) {
        float4 v = p[i];
        s += v.x * v.x + v.y * v.y + v.z * v.z + v.w * v.w;
    }
    csq[c] = s;
    cinit_h[c] = (_Float16)(SBIAS - 0.5f * s);
}

// ---------------- prep: codebook -> f16 MFMA B-fragments ----------------
// B-operand of mfma_f32_16x16x32_f16: lane l holds B[k=(l>>4)*8+j][n=l&15].
// frag g = ((q*4+kb)*256+nt)*64+lane at bhi + g*8 halves.
__global__ void prep_frags(const float* __restrict__ cb, _Float16* __restrict__ bhi,
                           float* __restrict__ loss_accum) {
    int g = blockIdx.x * 256 + threadIdx.x;
    if (g == 0) loss_accum[0] = 0.f;
    int lane = g & 63;
    int nt   = (g >> 6) & 255;
    int kb   = (g >> 14) & 3;
    int q    = g >> 16;
    int code = nt * 16 + (lane & 15);
    int k0   = kb * 32 + ((lane >> 4) * 8);
    const float* src = cb + ((size_t)q * KCODES + code) * DIMS + k0;
    float4 v0 = *(const float4*)(src);
    float4 v1 = *(const float4*)(src + 4);
    half8 h;
    h[0] = (_Float16)v0.x; h[1] = (_Float16)v0.y; h[2] = (_Float16)v0.z; h[3] = (_Float16)v0.w;
    h[4] = (_Float16)v1.x; h[5] = (_Float16)v1.y; h[6] = (_Float16)v1.z; h[7] = (_Float16)v1.w;
    *(half8*)(bhi + (size_t)g * 8) = h;
}

// One pipeline phase p, read slot S = p&3, WRITE slot SW = (p+3)&3 (ROUND-11
// BUG FIX: previously wrote slot S — raced this phase's own reads and left
// slot 3 uninitialized at q=0 -> NaN keys -> bi=KCODES -> OOB cb read -> abort).
// Invariant at entry: 3 loads outstanding (issued at p-3,p-2,p-1); vmcnt(2)
// -> the p-3 issue (this phase's tile, slot S) landed; barrier -> all waves'
// slot-S pieces landed AND all waves consumed slot SW's reads in phase p-1
// (their lgkm drained before their barrier) -> safe to overwrite slot SW.
#define PHASE(S, SW)                                                           \
  do {                                                                         \
    asm volatile("s_waitcnt vmcnt(2)" ::: "memory");                           \
    __builtin_amdgcn_s_barrier();                                              \
    __builtin_amdgcn_sched_barrier(0);                                         \
    gload16(gsrc, stgDst + (SW) * 8192);                                       \
    gsrc += 1024;                                                              \
    const half8* sp = (const half8*)(stgRd + (S) * 8192);                      \
    half8 b0 = sp[0], b1 = sp[64], b2 = sp[128], b3 = sp[192];                 \
    float csv = (float)*csp; csp += 16;                                        \
    float4v acc; acc[0] = csv; acc[1] = csv; acc[2] = csv; acc[3] = csv;       \
    __builtin_amdgcn_s_setprio(1);                                             \
    acc = __builtin_amdgcn_mfma_f32_16x16x32_f16(ahi0, b0, acc, 0, 0, 0);      \
    acc = __builtin_amdgcn_mfma_f32_16x16x32_f16(ahi1, b1, acc, 0, 0, 0);      \
    acc = __builtin_amdgcn_mfma_f32_16x16x32_f16(ahi2, b2, acc, 0, 0, 0);      \
    acc = __builtin_amdgcn_mfma_f32_16x16x32_f16(ahi3, b3, acc, 0, 0, 0);      \
    __builtin_amdgcn_s_setprio(0);                                             \
    _Pragma("unroll")                                                          \
    for (int r = 0; r < 4; ++r) {                                              \
      unsigned pk = (__float_as_uint(acc[r]) & 0xFFFFF000u) | idxv;            \
      unsigned o1 = p1[r], o2 = p2[r];                                         \
      p1[r] = umax_(o1, pk);                                                   \
      asm("v_med3_u32 %0, %1, %2, %3" : "=v"(p2[r]) : "v"(pk), "v"(o1), "v"(o2)); \
      asm("v_med3_u32 %0, %1, %2, %3" : "=v"(p3[r]) : "v"(pk), "v"(o2), "v"(p3[r])); \
    }                                                                          \
    idxv += 16u;                                                               \
  } while (0)

// (512,4): 4 waves/EU -> VGPR cap 128. 2D wave split keeps live state ~80:
// ahi 16 + b 16 + p1..p3 12 + acc 4 + addr/misc. 2 blocks/CU = 16 waves/CU.
__launch_bounds__(NTHREADS, 4)
__global__ void rvq_main(const float* __restrict__ x, const float* __restrict__ cb,
                         const _Float16* __restrict__ bhi,
                         const float* __restrict__ csq, const _Float16* __restrict__ cinit_h,
                         float* __restrict__ out, float* __restrict__ loss_accum) {
    __shared__ float res[TM][RESPAD];                   // 33792 B
    __shared__ __align__(16) char stg[4 * 8192];        // B ring, 4 slots (32768 B)
    __shared__ __align__(16) _Float16 cinq_lds[KCODES]; // f16 cinit (8192 B)
    __shared__ float fbin[TM];                          // 256 B
    // overlays on stg (dead after screen loop, barrier-separated):
    unsigned (*cand)[CANDROW] = reinterpret_cast<unsigned (*)[CANDROW]>(&stg[0]); // 24832 B
    float* red = reinterpret_cast<float*>(&stg[0] + 25600);                       // 2048 B
    // static LDS = 75008 B -> 2 blocks/CU

    int tid  = threadIdx.x;
    int lane = tid & 63;
    int wv   = tid >> 6;        // 0..7
    int rg   = wv & 3;          // row-group: rows rg*16..rg*16+15
    int ch   = wv >> 2;         // code-half: tiles ch*128..ch*128+127
    int col  = lane & 15;
    int r0   = blockIdx.x * TM;
    int b    = r0 >> 12;
    int n0   = r0 & (SEQ - 1);
    const float* xb = x + (size_t)b * DIMS * SEQ + n0;

    // stage ownership: wave wv DMAs kb=(wv&3) of half (wv>>2), 1 KB/phase
    int kbS = wv & 3, chS = wv >> 2;
    char* stgDst = &stg[0] + chS * 4096 + kbS * 1024;            // wave-uniform
    const char* stgRd = &stg[0] + ch * 4096 + lane * 16;

    // load x[b][d][n0..n0+63] into res[n][d]: 4 threads per d, 16 floats each
    {
        int d = tid >> 2, quarter = (tid & 3) * 16;
        const float* src = xb + (size_t)d * SEQ + quarter;
#pragma unroll
        for (int t4 = 0; t4 < 4; ++t4) {
            float4 v = *(const float4*)(src + t4 * 4);
            res[quarter + t4 * 4 + 0][d] = v.x;
            res[quarter + t4 * 4 + 1][d] = v.y;
            res[quarter + t4 * 4 + 2][d] = v.z;
            res[quarter + t4 * 4 + 3][d] = v.w;
        }
    }
    __syncthreads();

    float lossacc = 0.f;

    for (int q = 0; q < NQ; ++q) {
        const _Float16* bq   = bhi + (size_t)q * FRAGQ;
        const _Float16* cq   = cinit_h + q * KCODES;
        const float*    csqq = csq + q * KCODES;

        // ---- prologue DMAs (4 outstanding: cinq + slots 0..2 = tiles 0..2) ----
        gload16((const char*)cq + wv * 1024 + lane * 16, (char*)cinq_lds + wv * 1024);
        const char* gsrc = (const char*)bq +
            (((size_t)(kbS * 256 + chS * 128 + 3) * 64 + lane) << 4); // phase-3 src
        gload16(gsrc - 3072, stgDst + 0 * 8192);   // tile 0 -> slot 0
        gload16(gsrc - 2048, stgDst + 1 * 8192);   // tile 1 -> slot 1
        gload16(gsrc - 1024, stgDst + 2 * 8192);   // tile 2 -> slot 2

        // ---- A fragments (16 rows/wave) — covers prologue DMA latency ----
        half8 ahi0, ahi1, ahi2, ahi3;
        {
            int arow = rg * 16 + col;
            int kg   = (lane >> 4) * 8;
#pragma unroll
            for (int kb = 0; kb < 4; ++kb) {
                float4 v0 = *(const float4*)&res[arow][kb * 32 + kg];
                float4 v1 = *(const float4*)&res[arow][kb * 32 + kg + 4];
                half8 h;
                h[0]=(_Float16)v0.x; h[1]=(_Float16)v0.y; h[2]=(_Float16)v0.z; h[3]=(_Float16)v0.w;
                h[4]=(_Float16)v1.x; h[5]=(_Float16)v1.y; h[6]=(_Float16)v1.z; h[7]=(_Float16)v1.w;
                if (kb == 0) ahi0 = h; else if (kb == 1) ahi1 = h;
                else if (kb == 2) ahi2 = h; else ahi3 = h;
            }
        }

        unsigned p1[4], p2[4], p3[4];
#pragma unroll
        for (int r = 0; r < 4; ++r) { p1[r] = 0u; p2[r] = 0u; p3[r] = 0u; }

        unsigned idxv = (unsigned)((ch * 128) * 16 + col);
        const _Float16* csp = cinq_lds + (ch * 128) * 16 + col;

        // ---- 128 phases, 4-slot ring, counted vmcnt(2) ----
        // PHASE(read S, write (S+3)&3): p0 issues tile3->slot3, p1 tile4->slot0, ...
        for (int p4 = 0; p4 < 128; p4 += 4) {
            PHASE(0, 3); PHASE(1, 0); PHASE(2, 1); PHASE(3, 2);
        }
        // 3 dangling tail loads (~3 KB into the bhi tail pad) drain here:
        __syncthreads();   // vmcnt(0) -> tail DMA writes to stg landed before cand overlay

        // ---- candidates: best-3 per (col, half) slice, direct write ----
        {
            int crow  = rg * 16 + (lane >> 4) * 4;
            int cbase = (ch * 16 + col) * 3;
#pragma unroll
            for (int r = 0; r < 4; ++r) {
                cand[crow + r][cbase + 0] = p1[r];
                cand[crow + r][cbase + 1] = p2[r];
                cand[crow + r][cbase + 2] = p3[r];
            }
        }
        __syncthreads();

        // ---- exact f32 refine: 8 threads/row x 12 entries ----
        {
            int row = tid >> 3, s = tid & 7;
            const unsigned* cp = &cand[row][s * 12];
            unsigned m = 0;
#pragma unroll
            for (int k = 0; k < 12; ++k) m = umax_(m, cp[k]);
            m = umax_(m, (unsigned)__shfl_xor((int)m, 1, 64));
            m = umax_(m, (unsigned)__shfl_xor((int)m, 2, 64));
            m = umax_(m, (unsigned)__shfl_xor((int)m, 4, 64));
            float thr = __uint_as_float(m) - WIN;
            float bk = -3.4e38f;
            int   bi = KCODES;
            const float4* rv = (const float4*)&res[row][0];
            for (int k = 0; k < 12; ++k) {
                unsigned e = cp[k];
                if (__uint_as_float(e) >= thr) {
                    int idx = (int)(e & 0xFFFu);
                    const float4* cv = (const float4*)(cb + ((size_t)q * KCODES + idx) * DIMS);
                    float acc = 0.f;
#pragma unroll
                    for (int jj = 0; jj < 32; ++jj) {
                        float4 c4 = cv[jj];
                        float4 r4 = rv[jj];
                        acc = fmaf(r4.x, c4.x, acc);
                        acc = fmaf(r4.y, c4.y, acc);
                        acc = fmaf(r4.z, c4.z, acc);
                        acc = fmaf(r4.w, c4.w, acc);
                    }
                    float key = acc - 0.5f * csqq[idx];
                    if (key > bk || (key == bk && idx < bi)) { bk = key; bi = idx; }
                }
            }
#pragma unroll
            for (int mask = 1; mask <= 4; mask <<= 1) {
                float ok = __shfl_xor(bk, mask, 64);
                int   oi = __shfl_xor(bi, mask, 64);
                if (ok > bk || (ok == bk && oi < bi)) { bk = ok; bi = oi; }
            }
            if (s == 0) {
                fbin[row] = (float)bi;
                out[OUT_ELEMS + (size_t)(r0 + row) * NQ + q] = (float)bi;
            }
        }
        __syncthreads();

        // ---- residual update + commitment loss: 8 threads/row x 16 floats ----
        {
            int row = tid >> 3, j = tid & 7;
            int bi = (int)fbin[row];
            if (bi >= KCODES) bi = KCODES - 1;   // OOB guard (never expected)
            const float* cv = cb + ((size_t)q * KCODES + bi) * DIMS + j * 16;
            float* rp = &res[row][j * 16];
#pragma unroll
            for (int t = 0; t < 4; ++t) {
                float4 c4 = *(const float4*)(cv + t * 4);
                float4 r4 = *(const float4*)(rp + t * 4);
                r4.x -= c4.x; lossacc = fmaf(r4.x, r4.x, lossacc);
                r4.y -= c4.y; lossacc = fmaf(r4.y, r4.y, lossacc);
                r4.z -= c4.z; lossacc = fmaf(r4.z, r4.z, lossacc);
                r4.w -= c4.w; lossacc = fmaf(r4.w, r4.w, lossacc);
                *(float4*)(rp + t * 4) = r4;
            }
        }
        __syncthreads();   // res/cand/stg settled for next q
    }

    // ---- loss reduction (red overlays stg) ----
    red[tid] = lossacc;
    __syncthreads();
    for (int s = NTHREADS / 2; s > 0; s >>= 1) {
        if (tid < s) red[tid] += red[tid + s];
        __syncthreads();
    }
    if (tid == 0) atomicAdd(loss_accum, red[0]);

    // ---- quantized output: out = x - final_residual ----
    {
        int d = tid >> 2, quarter = (tid & 3) * 16;
        const float* src = xb + (size_t)d * SEQ + quarter;
        float* dst = out + (size_t)b * DIMS * SEQ + (size_t)d * SEQ + n0 + quarter;
#pragma unroll
        for (int t4 = 0; t4 < 4; ++t4) {
            float4 v = *(const float4*)(src + t4 * 4);
            v.x -= res[quarter + t4 * 4 + 0][d];
            v.y -= res[quarter + t4 * 4 + 1][d];
            v.z -= res[quarter + t4 * 4 + 2][d];
            v.w -= res[quarter + t4 * 4 + 3][d];
            *(float4*)(dst + t4 * 4) = v;
        }
    }
}

__global__ void finish_loss(const float* __restrict__ loss_accum, float* __restrict__ out) {
    out[OUT_ELEMS + IDX_ELEMS] = loss_accum[0] * LOSS_DIV;
}

extern "C" void kernel_launch(void* const* d_in, const int* in_sizes, int n_in,
                              void* d_out, int out_size, void* d_ws, size_t ws_size,
                              hipStream_t stream) {
    const float* x  = (const float*)d_in[0];
    const float* cb = (const float*)d_in[1];
    float* out = (float*)d_out;
    char*  ws  = (char*)d_ws;

    float*     loss_accum = (float*)ws;
    float*     csq     = (float*)(ws + 256);                       // 131072 B
    _Float16*  cinit_h = (_Float16*)(ws + 256 + 131072);           // 65536 B
    _Float16*  bhi     = (_Float16*)(ws + 256 + 131072 + 65536);   // 8 MB (+16KB
                                 // tail pad: last-q prefetch overreach lands here)

    hipLaunchKernelGGL(prep_csq,   dim3(128),  dim3(256), 0, stream, cb, csq, cinit_h);
    hipLaunchKernelGGL(prep_frags, dim3(2048), dim3(256), 0, stream, cb, bhi, loss_accum);
    hipLaunchKernelGGL(rvq_main,   dim3(NBLK), dim3(NTHREADS), 0, stream,
                       x, cb, bhi, csq, cinit_h, out, loss_accum);
    hipLaunchKernelGGL(finish_loss, dim3(1), dim3(1), 0, stream, loss_accum, out);
}

// Round 15
// 523.771 us; speedup vs baseline: 2.4398x; 1.4340x over previous
//
#include <hip/hip_runtime.h>

typedef _Float16 half8 __attribute__((ext_vector_type(8)));
typedef float    float4v __attribute__((ext_vector_type(4)));
typedef unsigned int u32;

#define NQ 8
#define KCODES 4096
#define DIMS 128
#define BATCH 8
#define SEQ 4096
#define ROWS (BATCH*SEQ)            // 32768
#define TM 64                       // rows per block
#define NBLK (ROWS/TM)              // 512 = 2 blocks/CU
#define RESPAD 132                  // res row stride (floats)
#define CANDROW 67                  // cand row stride (uints)
#define OUT_ELEMS (BATCH*DIMS*SEQ)  // 4194304
#define IDX_ELEMS (BATCH*SEQ*NQ)    // 262144
#define LOSS_DIV (1.0f/33554432.0f) // 1/(Q*B*N*D)
#define FRAGQ ((size_t)4*256*64*8)  // halves per q-stage of bhi (1 MB)
#define SBIAS 384.0f                // key bias: keys = dot - csq/2 + 384, ~[240,450] > 0
#define WIN 2.0f                    // refine window — PROVEN value (rounds 1-10)

__device__ __forceinline__ unsigned umax_(unsigned a, unsigned b){ return a>b?a:b; }
__device__ __forceinline__ unsigned umin_(unsigned a, unsigned b){ return a<b?a:b; }

// async global->LDS DMA (cinq slice only; vmcnt-tracked, issued first)
__device__ __forceinline__ void gload16(const void* g, void* l) {
    __builtin_amdgcn_global_load_lds(
        (const __attribute__((address_space(1))) u32*)g,
        (__attribute__((address_space(3))) u32*)l, 16, 0, 0);
}

// asm-pinned B loads: "=v" outputs pin dest regs (regalloc can't collapse depth)
#define B_ISSUE(X0,X1,X2,X3,OFF)                                              \
    asm volatile("global_load_dwordx4 %0, %4, %8 offset:" #OFF "\n\t"         \
                 "global_load_dwordx4 %1, %5, %8 offset:" #OFF "\n\t"         \
                 "global_load_dwordx4 %2, %6, %8 offset:" #OFF "\n\t"         \
                 "global_load_dwordx4 %3, %7, %8 offset:" #OFF                \
                 : "=v"(X0), "=v"(X1), "=v"(X2), "=v"(X3)                     \
                 : "v"(vo0), "v"(vo1), "v"(vo2), "v"(vo3), "s"(bq))

// counted wait: the set issued 3 tiles ago has landed. "+v" deps order it.
#define B_WAIT(X0,X1,X2,X3)                                                   \
    asm volatile("s_waitcnt vmcnt(8)"                                         \
                 : "+v"(X0), "+v"(X1), "+v"(X2), "+v"(X3))

// ---------------- prep: csq f32 ; cinit_h = f16(384 - csq/2) ----------------
__global__ void prep_csq(const float* __restrict__ cb, float* __restrict__ csq,
                         _Float16* __restrict__ cinit_h) {
    int c = blockIdx.x * 256 + threadIdx.x;
    const float4* p = (const float4*)(cb + (size_t)c * DIMS);
    float s = 0.f;
#pragma unroll
    for (int i = 0; i < 32; ++i) {
        float4 v = p[i];
        s += v.x * v.x + v.y * v.y + v.z * v.z + v.w * v.w;
    }
    csq[c] = s;
    cinit_h[c] = (_Float16)(SBIAS - 0.5f * s);
}

// ---------------- prep: codebook -> f16 MFMA B-fragments ----------------
__global__ void prep_frags(const float* __restrict__ cb, _Float16* __restrict__ bhi,
                           float* __restrict__ loss_accum) {
    int g = blockIdx.x * 256 + threadIdx.x;
    if (g == 0) loss_accum[0] = 0.f;
    int lane = g & 63;
    int nt   = (g >> 6) & 255;
    int kb   = (g >> 14) & 3;
    int q    = g >> 16;
    int code = nt * 16 + (lane & 15);
    int k0   = kb * 32 + ((lane >> 4) * 8);
    const float* src = cb + ((size_t)q * KCODES + code) * DIMS + k0;
    float4 v0 = *(const float4*)(src);
    float4 v1 = *(const float4*)(src + 4);
    half8 h;
    h[0] = (_Float16)v0.x; h[1] = (_Float16)v0.y; h[2] = (_Float16)v0.z; h[3] = (_Float16)v0.w;
    h[4] = (_Float16)v1.x; h[5] = (_Float16)v1.y; h[6] = (_Float16)v1.z; h[7] = (_Float16)v1.w;
    *(half8*)(bhi + (size_t)g * 8) = h;
}

// 16 MFMA + best-2 insert (proven round-10 form)
__device__ __forceinline__ void compute16(
        const half8& b0, const half8& b1, const half8& b2, const half8& b3,
        float csv, unsigned idxv, const half8 (&ahi)[4][4],
        unsigned (&p1)[4][4], unsigned (&p2)[4][4]) {
    float4v acc[4];
#pragma unroll
    for (int mt = 0; mt < 4; ++mt) { acc[mt][0]=csv; acc[mt][1]=csv; acc[mt][2]=csv; acc[mt][3]=csv; }
    __builtin_amdgcn_s_setprio(1);
#pragma unroll
    for (int mt = 0; mt < 4; ++mt) acc[mt] = __builtin_amdgcn_mfma_f32_16x16x32_f16(ahi[mt][0], b0, acc[mt], 0, 0, 0);
#pragma unroll
    for (int mt = 0; mt < 4; ++mt) acc[mt] = __builtin_amdgcn_mfma_f32_16x16x32_f16(ahi[mt][1], b1, acc[mt], 0, 0, 0);
#pragma unroll
    for (int mt = 0; mt < 4; ++mt) acc[mt] = __builtin_amdgcn_mfma_f32_16x16x32_f16(ahi[mt][2], b2, acc[mt], 0, 0, 0);
#pragma unroll
    for (int mt = 0; mt < 4; ++mt) acc[mt] = __builtin_amdgcn_mfma_f32_16x16x32_f16(ahi[mt][3], b3, acc[mt], 0, 0, 0);
    __builtin_amdgcn_s_setprio(0);
#pragma unroll
    for (int mt = 0; mt < 4; ++mt)
#pragma unroll
        for (int r = 0; r < 4; ++r) {
            unsigned pk   = (__float_as_uint(acc[mt][r]) & 0xFFFFF000u) | idxv;
            unsigned old1 = p1[mt][r];
            p1[mt][r] = umax_(old1, pk);
            p2[mt][r] = umax_(umin_(old1, pk), p2[mt][r]);
        }
}

__launch_bounds__(256, 2)
__global__ void rvq_main(const float* __restrict__ x, const float* __restrict__ cb,
                         const _Float16* __restrict__ bhi,
                         const float* __restrict__ csq, const _Float16* __restrict__ cinit_h,
                         float* __restrict__ out, float* __restrict__ loss_accum) {
    __shared__ float    res[TM][RESPAD];                 // 33792 B
    __shared__ __align__(16) _Float16 cinq_lds[KCODES];  // 8192 B
    __shared__ unsigned cand[TM][CANDROW];               // 17152 B
    __shared__ float    fbin[TM];                        // 256 B
    __shared__ float    red[256];                        // 1024 B
    // static LDS ~= 60.4 KB -> 2 blocks/CU

    int tid  = threadIdx.x;
    int lane = tid & 63;
    int wv   = tid >> 6;
    int col  = lane & 15;
    int r0   = blockIdx.x * TM;
    int b    = r0 >> 12;
    int n0   = r0 & (SEQ - 1);
    const float* xb = x + (size_t)b * DIMS * SEQ + n0;

    // load x[b][d][n0..n0+63] into res[n][d]
    {
        int d = tid >> 1, half = (tid & 1) * 32;
        const float* src = xb + (size_t)d * SEQ + half;
#pragma unroll
        for (int t4 = 0; t4 < 8; ++t4) {
            float4 v = *(const float4*)(src + t4 * 4);
            res[half + t4 * 4 + 0][d] = v.x;
            res[half + t4 * 4 + 1][d] = v.y;
            res[half + t4 * 4 + 2][d] = v.z;
            res[half + t4 * 4 + 3][d] = v.w;
        }
    }

    float lossacc = 0.f;
    int ntBase = wv * 64;

    for (int q = 0; q < NQ; ++q) {
        asm volatile("s_waitcnt lgkmcnt(0)" ::: "memory");
        __builtin_amdgcn_s_barrier();

        const _Float16* bq   = bhi + (size_t)q * FRAGQ;
        const _Float16* cq   = cinit_h + q * KCODES;
        const float*    csqq = csq + q * KCODES;

        {
            const _Float16* g0 = cq + wv * 1024 + lane * 8;
            gload16(g0,       (char*)cinq_lds + wv * 2048);
            gload16(g0 + 512, (char*)cinq_lds + wv * 2048 + 1024);
        }

        u32 vo0, vo1, vo2, vo3;
        {
            u32 base = (u32)(((ntBase + 3) * 64 + lane) << 4);
            vo0 = base;
            vo1 = base + (256u * 64u * 16u);
            vo2 = base + (512u * 64u * 16u);
            vo3 = base + (768u * 64u * 16u);
        }
        half8 a0,a1,a2,a3, b0,b1,b2,b3, c0,c1,c2,c3, d0,d1,d2,d3;
        B_ISSUE(a0,a1,a2,a3, -3072);
        B_ISSUE(b0,b1,b2,b3, -2048);
        B_ISSUE(c0,c1,c2,c3, -1024);
        // outstanding: cinq(2) + 12 = 14

        half8 ahi[4][4];
#pragma unroll
        for (int mt = 0; mt < 4; ++mt)
#pragma unroll
        for (int kb = 0; kb < 4; ++kb) {
            int row = mt * 16 + col;
            int k0  = kb * 32 + (lane >> 4) * 8;
            float4 v0 = *(const float4*)&res[row][k0];
            float4 v1 = *(const float4*)&res[row][k0 + 4];
            half8 h;
            h[0] = (_Float16)v0.x; h[1] = (_Float16)v0.y; h[2] = (_Float16)v0.z; h[3] = (_Float16)v0.w;
            h[4] = (_Float16)v1.x; h[5] = (_Float16)v1.y; h[6] = (_Float16)v1.z; h[7] = (_Float16)v1.w;
            ahi[mt][kb] = h;
        }
        // cinq DMA landed before cs reads (race fix, round 10)
        asm volatile("s_waitcnt vmcnt(12)" ::: "memory");

        unsigned p1[4][4], p2[4][4];
#pragma unroll
        for (int mt = 0; mt < 4; ++mt)
#pragma unroll
        for (int r = 0; r < 4; ++r) { p1[mt][r] = 0u; p2[mt][r] = 0u; }

        unsigned idx0 = (unsigned)(ntBase * 16 + col);

        // depth-3 pinned pipeline (round-9 structure, best measured)
        for (int ii = 0; ii < 16; ++ii) {
            int t = ii * 4;
            float cs0 = (float)cinq_lds[(ntBase + t + 0) * 16 + col];
            float cs1 = (float)cinq_lds[(ntBase + t + 1) * 16 + col];
            float cs2 = (float)cinq_lds[(ntBase + t + 2) * 16 + col];
            float cs3 = (float)cinq_lds[(ntBase + t + 3) * 16 + col];

            B_WAIT(a0,a1,a2,a3);
            B_ISSUE(d0,d1,d2,d3, 0);
            compute16(a0,a1,a2,a3, cs0, idx0 + (unsigned)(t+0)*16u, ahi, p1, p2);

            B_WAIT(b0,b1,b2,b3);
            B_ISSUE(a0,a1,a2,a3, 1024);
            compute16(b0,b1,b2,b3, cs1, idx0 + (unsigned)(t+1)*16u, ahi, p1, p2);

            B_WAIT(c0,c1,c2,c3);
            B_ISSUE(b0,b1,b2,b3, 2048);
            compute16(c0,c1,c2,c3, cs2, idx0 + (unsigned)(t+2)*16u, ahi, p1, p2);

            B_WAIT(d0,d1,d2,d3);
            B_ISSUE(c0,c1,c2,c3, 3072);
            compute16(d0,d1,d2,d3, cs3, idx0 + (unsigned)(t+3)*16u, ahi, p1, p2);

            vo0 += 4096; vo1 += 4096; vo2 += 4096; vo3 += 4096;
        }
        __syncthreads();   // drains 12 tail prefetches (land in bhi tail pad)

        // pair-merge best-2 across (lane, lane^1) -> top-2-of-128 slices
#pragma unroll
        for (int mt = 0; mt < 4; ++mt)
#pragma unroll
        for (int r = 0; r < 4; ++r) {
            unsigned q1 = p1[mt][r], q2 = p2[mt][r];
            unsigned o1 = (unsigned)__shfl_xor((int)q1, 1, 64);
            unsigned o2 = (unsigned)__shfl_xor((int)q2, 1, 64);
            unsigned n1 = umax_(q1, o1);
            unsigned n2 = umax_(umin_(q1, o1), umax_(q2, o2));
            if ((lane & 1) == 0) {
                int row = mt * 16 + (lane >> 4) * 4 + r;
                int cc  = wv * 16 + (col >> 1) * 2;
                cand[row][cc]     = n1;
                cand[row][cc + 1] = n2;
            }
        }
        __syncthreads();

        // exact f32 refine (PROVEN serial form): 4 threads/row scan 16 entries;
        // all entries within WIN of the row max get an exact f32 dot
        {
            int row = tid >> 2, s = tid & 3;
            const unsigned* cp = &cand[row][s * 16];
            unsigned m = 0;
#pragma unroll
            for (int k = 0; k < 16; ++k) m = umax_(m, cp[k]);
            m = umax_(m, (unsigned)__shfl_xor((int)m, 1, 64));
            m = umax_(m, (unsigned)__shfl_xor((int)m, 2, 64));
            float thr = __uint_as_float(m) - WIN;
            float bk = -3.4e38f;
            int   bi = KCODES - 1;
            const float4* rv = (const float4*)&res[row][0];
            for (int k = 0; k < 16; ++k) {
                unsigned e = cp[k];
                if (__uint_as_float(e) >= thr) {
                    int idx = (int)(e & 0xFFFu);
                    const float4* cv = (const float4*)(cb + ((size_t)q * KCODES + idx) * DIMS);
                    float acc = 0.f;
#pragma unroll
                    for (int jj = 0; jj < 32; ++jj) {
                        float4 c4 = cv[jj];
                        float4 r4 = rv[jj];
                        acc = fmaf(r4.x, c4.x, acc);
                        acc = fmaf(r4.y, c4.y, acc);
                        acc = fmaf(r4.z, c4.z, acc);
                        acc = fmaf(r4.w, c4.w, acc);
                    }
                    float key = acc - 0.5f * csqq[idx];
                    if (key > bk || (key == bk && idx < bi)) { bk = key; bi = idx; }
                }
            }
#pragma unroll
            for (int mask = 1; mask <= 2; mask <<= 1) {
                float ok = __shfl_xor(bk, mask, 64);
                int   oi = __shfl_xor(bi, mask, 64);
                if (ok > bk || (ok == bk && oi < bi)) { bk = ok; bi = oi; }
            }
            if (s == 0) {
                fbin[row] = (float)bi;
                out[OUT_ELEMS + (size_t)(r0 + row) * NQ + q] = (float)bi;
            }
        }
        __syncthreads();

        // residual update + commitment loss; contiguous 32-float chunk/thread
        {
            int row = tid >> 2, j = tid & 3;
            int bi = (int)fbin[row];
            if (bi >= KCODES) bi = KCODES - 1;   // OOB guard (inert when winner exists)
            const float* cv = cb + ((size_t)q * KCODES + bi) * DIMS + j * 32;
            float* rp = &res[row][j * 32];
#pragma unroll
            for (int t = 0; t < 8; ++t) {
                float4 c4 = *(const float4*)(cv + t * 4);
                float4 r4 = *(const float4*)(rp + t * 4);
                r4.x -= c4.x; lossacc = fmaf(r4.x, r4.x, lossacc);
                r4.y -= c4.y; lossacc = fmaf(r4.y, r4.y, lossacc);
                r4.z -= c4.z; lossacc = fmaf(r4.z, r4.z, lossacc);
                r4.w -= c4.w; lossacc = fmaf(r4.w, r4.w, lossacc);
                *(float4*)(rp + t * 4) = r4;
            }
        }
    }

    // loss reduction
    __syncthreads();
    red[tid] = lossacc;
    __syncthreads();
    for (int s = 128; s > 0; s >>= 1) {
        if (tid < s) red[tid] += red[tid + s];
        __syncthreads();
    }
    if (tid == 0) atomicAdd(loss_accum, red[0]);

    // quantized output: out = x - final_residual
    {
        int d = tid >> 1, half = (tid & 1) * 32;
        const float* src = xb + (size_t)d * SEQ + half;
        float* dst = out + (size_t)b * DIMS * SEQ + (size_t)d * SEQ + n0 + half;
#pragma unroll
        for (int t4 = 0; t4 < 8; ++t4) {
            float4 v = *(const float4*)(src + t4 * 4);
            v.x -= res[half + t4 * 4 + 0][d];
            v.y -= res[half + t4 * 4 + 1][d];
            v.z -= res[half + t4 * 4 + 2][d];
            v.w -= res[half + t4 * 4 + 3][d];
            *(float4*)(dst + t4 * 4) = v;
        }
    }
}

__global__ void finish_loss(const float* __restrict__ loss_accum, float* __restrict__ out) {
    out[OUT_ELEMS + IDX_ELEMS] = loss_accum[0] * LOSS_DIV;
}

extern "C" void kernel_launch(void* const* d_in, const int* in_sizes, int n_in,
                              void* d_out, int out_size, void* d_ws, size_t ws_size,
                              hipStream_t stream) {
    const float* x  = (const float*)d_in[0];
    const float* cb = (const float*)d_in[1];
    float* out = (float*)d_out;
    char*  ws  = (char*)d_ws;

    float*     loss_accum = (float*)ws;
    float*     csq     = (float*)(ws + 256);                       // 131072 B
    _Float16*  cinit_h = (_Float16*)(ws + 256 + 131072);           // 65536 B
    _Float16*  bhi     = (_Float16*)(ws + 256 + 131072 + 65536);   // 8 MB (+16KB
                                 // tail pad: last-q prefetch overreach lands here)

    hipLaunchKernelGGL(prep_csq,   dim3(128),  dim3(256), 0, stream, cb, csq, cinit_h);
    hipLaunchKernelGGL(prep_frags, dim3(2048), dim3(256), 0, stream, cb, bhi, loss_accum);
    hipLaunchKernelGGL(rvq_main,   dim3(NBLK), dim3(256), 0, stream,
                       x, cb, bhi, csq, cinit_h, out, loss_accum);
    hipLaunchKernelGGL(finish_loss, dim3(1), dim3(1), 0, stream, loss_accum, out);
}

// Round 16
// 521.220 us; speedup vs baseline: 2.4517x; 1.0049x over previous
//
#include <hip/hip_runtime.h>

typedef _Float16 half8 __attribute__((ext_vector_type(8)));
typedef float    float4v __attribute__((ext_vector_type(4)));
typedef unsigned int u32;

#define NQ 8
#define KCODES 4096
#define DIMS 128
#define BATCH 8
#define SEQ 4096
#define ROWS (BATCH*SEQ)            // 32768
#define TM 64                       // rows per block
#define NBLK (ROWS/TM)              // 512 = 2 blocks/CU
#define RESPAD 132                  // res row stride (floats)
#define CANDROW 67                  // cand row stride (uints)
#define OUT_ELEMS (BATCH*DIMS*SEQ)  // 4194304
#define IDX_ELEMS (BATCH*SEQ*NQ)    // 262144
#define LOSS_DIV (1.0f/33554432.0f) // 1/(Q*B*N*D)
#define FRAGQ ((size_t)4*256*64*8)  // halves per q-stage of bhi (1 MB)
#define SBIAS 384.0f                // key bias: keys = dot - csq/2 + 384, ~[240,450] > 0
#define WIN 2.0f                    // refine window — PROVEN value (rounds 1-10)

__device__ __forceinline__ unsigned umax_(unsigned a, unsigned b){ return a>b?a:b; }
__device__ __forceinline__ unsigned umin_(unsigned a, unsigned b){ return a<b?a:b; }

// async global->LDS DMA (cinq slice only; vmcnt-tracked, issued first)
__device__ __forceinline__ void gload16(const void* g, void* l) {
    __builtin_amdgcn_global_load_lds(
        (const __attribute__((address_space(1))) u32*)g,
        (__attribute__((address_space(3))) u32*)l, 16, 0, 0);
}

// asm-pinned B loads: "=v" outputs pin dest regs (regalloc can't collapse depth)
#define B_ISSUE(X0,X1,X2,X3,OFF)                                              \
    asm volatile("global_load_dwordx4 %0, %4, %8 offset:" #OFF "\n\t"         \
                 "global_load_dwordx4 %1, %5, %8 offset:" #OFF "\n\t"         \
                 "global_load_dwordx4 %2, %6, %8 offset:" #OFF "\n\t"         \
                 "global_load_dwordx4 %3, %7, %8 offset:" #OFF                \
                 : "=v"(X0), "=v"(X1), "=v"(X2), "=v"(X3)                     \
                 : "v"(vo0), "v"(vo1), "v"(vo2), "v"(vo3), "s"(bq))

// counted wait: the set issued 3 tiles ago has landed. "+v" deps order it.
#define B_WAIT(X0,X1,X2,X3)                                                   \
    asm volatile("s_waitcnt vmcnt(8)"                                         \
                 : "+v"(X0), "+v"(X1), "+v"(X2), "+v"(X3))

// ---------------- prep: csq f32 ; cinit_h = f16(384 - csq/2) ----------------
__global__ void prep_csq(const float* __restrict__ cb, float* __restrict__ csq,
                         _Float16* __restrict__ cinit_h) {
    int c = blockIdx.x * 256 + threadIdx.x;
    const float4* p = (const float4*)(cb + (size_t)c * DIMS);
    float s = 0.f;
#pragma unroll
    for (int i = 0; i < 32; ++i) {
        float4 v = p[i];
        s += v.x * v.x + v.y * v.y + v.z * v.z + v.w * v.w;
    }
    csq[c] = s;
    cinit_h[c] = (_Float16)(SBIAS - 0.5f * s);
}

// ---------------- prep: codebook -> f16 MFMA B-fragments ----------------
__global__ void prep_frags(const float* __restrict__ cb, _Float16* __restrict__ bhi,
                           float* __restrict__ loss_accum) {
    int g = blockIdx.x * 256 + threadIdx.x;
    if (g == 0) loss_accum[0] = 0.f;
    int lane = g & 63;
    int nt   = (g >> 6) & 255;
    int kb   = (g >> 14) & 3;
    int q    = g >> 16;
    int code = nt * 16 + (lane & 15);
    int k0   = kb * 32 + ((lane >> 4) * 8);
    const float* src = cb + ((size_t)q * KCODES + code) * DIMS + k0;
    float4 v0 = *(const float4*)(src);
    float4 v1 = *(const float4*)(src + 4);
    half8 h;
    h[0] = (_Float16)v0.x; h[1] = (_Float16)v0.y; h[2] = (_Float16)v0.z; h[3] = (_Float16)v0.w;
    h[4] = (_Float16)v1.x; h[5] = (_Float16)v1.y; h[6] = (_Float16)v1.z; h[7] = (_Float16)v1.w;
    *(half8*)(bhi + (size_t)g * 8) = h;
}

// 16 MFMA + best-2 insert. NEW (this round): med3 form — 3 VALU/key vs 4.
// p2' = med3(p1_old, pk, p2_old) == max(min(p1_old,pk), p2_old), verified by
// case split incl. invariant p2<=p1 and zero-init (first key leaves p2=0).
__device__ __forceinline__ void compute16(
        const half8& b0, const half8& b1, const half8& b2, const half8& b3,
        float csv, unsigned idxv, const half8 (&ahi)[4][4],
        unsigned (&p1)[4][4], unsigned (&p2)[4][4]) {
    float4v acc[4];
#pragma unroll
    for (int mt = 0; mt < 4; ++mt) { acc[mt][0]=csv; acc[mt][1]=csv; acc[mt][2]=csv; acc[mt][3]=csv; }
    __builtin_amdgcn_s_setprio(1);
#pragma unroll
    for (int mt = 0; mt < 4; ++mt) acc[mt] = __builtin_amdgcn_mfma_f32_16x16x32_f16(ahi[mt][0], b0, acc[mt], 0, 0, 0);
#pragma unroll
    for (int mt = 0; mt < 4; ++mt) acc[mt] = __builtin_amdgcn_mfma_f32_16x16x32_f16(ahi[mt][1], b1, acc[mt], 0, 0, 0);
#pragma unroll
    for (int mt = 0; mt < 4; ++mt) acc[mt] = __builtin_amdgcn_mfma_f32_16x16x32_f16(ahi[mt][2], b2, acc[mt], 0, 0, 0);
#pragma unroll
    for (int mt = 0; mt < 4; ++mt) acc[mt] = __builtin_amdgcn_mfma_f32_16x16x32_f16(ahi[mt][3], b3, acc[mt], 0, 0, 0);
    __builtin_amdgcn_s_setprio(0);
#pragma unroll
    for (int mt = 0; mt < 4; ++mt)
#pragma unroll
        for (int r = 0; r < 4; ++r) {
            unsigned pk   = (__float_as_uint(acc[mt][r]) & 0xFFFFF000u) | idxv;
            unsigned old1 = p1[mt][r];
            p1[mt][r] = umax_(old1, pk);
            asm("v_med3_u32 %0, %1, %2, %3"
                : "=v"(p2[mt][r]) : "v"(old1), "v"(pk), "v"(p2[mt][r]));
        }
}

__launch_bounds__(256, 2)
__global__ void rvq_main(const float* __restrict__ x, const float* __restrict__ cb,
                         const _Float16* __restrict__ bhi,
                         const float* __restrict__ csq, const _Float16* __restrict__ cinit_h,
                         float* __restrict__ out, float* __restrict__ loss_accum) {
    __shared__ float    res[TM][RESPAD];                 // 33792 B
    __shared__ __align__(16) _Float16 cinq_lds[KCODES];  // 8192 B
    __shared__ unsigned cand[TM][CANDROW];               // 17152 B
    __shared__ float    fbin[TM];                        // 256 B
    __shared__ float    red[256];                        // 1024 B
    // static LDS ~= 60.4 KB -> 2 blocks/CU

    int tid  = threadIdx.x;
    int lane = tid & 63;
    int wv   = tid >> 6;
    int col  = lane & 15;
    int r0   = blockIdx.x * TM;
    int b    = r0 >> 12;
    int n0   = r0 & (SEQ - 1);
    const float* xb = x + (size_t)b * DIMS * SEQ + n0;

    // load x[b][d][n0..n0+63] into res[n][d]
    {
        int d = tid >> 1, half = (tid & 1) * 32;
        const float* src = xb + (size_t)d * SEQ + half;
#pragma unroll
        for (int t4 = 0; t4 < 8; ++t4) {
            float4 v = *(const float4*)(src + t4 * 4);
            res[half + t4 * 4 + 0][d] = v.x;
            res[half + t4 * 4 + 1][d] = v.y;
            res[half + t4 * 4 + 2][d] = v.z;
            res[half + t4 * 4 + 3][d] = v.w;
        }
    }

    float lossacc = 0.f;
    int ntBase = wv * 64;

    for (int q = 0; q < NQ; ++q) {
        asm volatile("s_waitcnt lgkmcnt(0)" ::: "memory");
        __builtin_amdgcn_s_barrier();

        const _Float16* bq   = bhi + (size_t)q * FRAGQ;
        const _Float16* cq   = cinit_h + q * KCODES;
        const float*    csqq = csq + q * KCODES;

        {
            const _Float16* g0 = cq + wv * 1024 + lane * 8;
            gload16(g0,       (char*)cinq_lds + wv * 2048);
            gload16(g0 + 512, (char*)cinq_lds + wv * 2048 + 1024);
        }

        u32 vo0, vo1, vo2, vo3;
        {
            u32 base = (u32)(((ntBase + 3) * 64 + lane) << 4);
            vo0 = base;
            vo1 = base + (256u * 64u * 16u);
            vo2 = base + (512u * 64u * 16u);
            vo3 = base + (768u * 64u * 16u);
        }
        half8 a0,a1,a2,a3, b0,b1,b2,b3, c0,c1,c2,c3, d0,d1,d2,d3;
        B_ISSUE(a0,a1,a2,a3, -3072);
        B_ISSUE(b0,b1,b2,b3, -2048);
        B_ISSUE(c0,c1,c2,c3, -1024);
        // outstanding: cinq(2) + 12 = 14

        half8 ahi[4][4];
#pragma unroll
        for (int mt = 0; mt < 4; ++mt)
#pragma unroll
        for (int kb = 0; kb < 4; ++kb) {
            int row = mt * 16 + col;
            int k0  = kb * 32 + (lane >> 4) * 8;
            float4 v0 = *(const float4*)&res[row][k0];
            float4 v1 = *(const float4*)&res[row][k0 + 4];
            half8 h;
            h[0] = (_Float16)v0.x; h[1] = (_Float16)v0.y; h[2] = (_Float16)v0.z; h[3] = (_Float16)v0.w;
            h[4] = (_Float16)v1.x; h[5] = (_Float16)v1.y; h[6] = (_Float16)v1.z; h[7] = (_Float16)v1.w;
            ahi[mt][kb] = h;
        }
        // cinq DMA landed before cs reads (race fix, round 10)
        asm volatile("s_waitcnt vmcnt(12)" ::: "memory");

        unsigned p1[4][4], p2[4][4];
#pragma unroll
        for (int mt = 0; mt < 4; ++mt)
#pragma unroll
        for (int r = 0; r < 4; ++r) { p1[mt][r] = 0u; p2[mt][r] = 0u; }

        unsigned idx0 = (unsigned)(ntBase * 16 + col);

        // cs values for super-iter 0 (tiles 0..3), preloaded (software pipeline)
        float cs0 = (float)cinq_lds[(ntBase + 0) * 16 + col];
        float cs1 = (float)cinq_lds[(ntBase + 1) * 16 + col];
        float cs2 = (float)cinq_lds[(ntBase + 2) * 16 + col];
        float cs3 = (float)cinq_lds[(ntBase + 3) * 16 + col];

        // depth-3 pinned pipeline (round-9 structure, best measured).
        // NEW (this round): cs loads for super-iter ii+1 issued at top of ii
        // (~2000 cyc early; &63 wrap keeps dead iter-15 prefetch in-bounds).
        for (int ii = 0; ii < 16; ++ii) {
            int t = ii * 4;
            float csn0 = (float)cinq_lds[(ntBase + ((t + 4) & 63)) * 16 + col];
            float csn1 = (float)cinq_lds[(ntBase + ((t + 5) & 63)) * 16 + col];
            float csn2 = (float)cinq_lds[(ntBase + ((t + 6) & 63)) * 16 + col];
            float csn3 = (float)cinq_lds[(ntBase + ((t + 7) & 63)) * 16 + col];

            B_WAIT(a0,a1,a2,a3);
            B_ISSUE(d0,d1,d2,d3, 0);
            compute16(a0,a1,a2,a3, cs0, idx0 + (unsigned)(t+0)*16u, ahi, p1, p2);

            B_WAIT(b0,b1,b2,b3);
            B_ISSUE(a0,a1,a2,a3, 1024);
            compute16(b0,b1,b2,b3, cs1, idx0 + (unsigned)(t+1)*16u, ahi, p1, p2);

            B_WAIT(c0,c1,c2,c3);
            B_ISSUE(b0,b1,b2,b3, 2048);
            compute16(c0,c1,c2,c3, cs2, idx0 + (unsigned)(t+2)*16u, ahi, p1, p2);

            B_WAIT(d0,d1,d2,d3);
            B_ISSUE(c0,c1,c2,c3, 3072);
            compute16(d0,d1,d2,d3, cs3, idx0 + (unsigned)(t+3)*16u, ahi, p1, p2);

            cs0 = csn0; cs1 = csn1; cs2 = csn2; cs3 = csn3;
            vo0 += 4096; vo1 += 4096; vo2 += 4096; vo3 += 4096;
        }
        __syncthreads();   // drains 12 tail prefetches (land in bhi tail pad)

        // pair-merge best-2 across (lane, lane^1) -> top-2-of-128 slices
#pragma unroll
        for (int mt = 0; mt < 4; ++mt)
#pragma unroll
        for (int r = 0; r < 4; ++r) {
            unsigned q1 = p1[mt][r], q2 = p2[mt][r];
            unsigned o1 = (unsigned)__shfl_xor((int)q1, 1, 64);
            unsigned o2 = (unsigned)__shfl_xor((int)q2, 1, 64);
            unsigned n1 = umax_(q1, o1);
            unsigned n2 = umax_(umin_(q1, o1), umax_(q2, o2));
            if ((lane & 1) == 0) {
                int row = mt * 16 + (lane >> 4) * 4 + r;
                int cc  = wv * 16 + (col >> 1) * 2;
                cand[row][cc]     = n1;
                cand[row][cc + 1] = n2;
            }
        }
        __syncthreads();

        // exact f32 refine (PROVEN serial form): 4 threads/row scan 16 entries;
        // all entries within WIN of the row max get an exact f32 dot
        {
            int row = tid >> 2, s = tid & 3;
            const unsigned* cp = &cand[row][s * 16];
            unsigned m = 0;
#pragma unroll
            for (int k = 0; k < 16; ++k) m = umax_(m, cp[k]);
            m = umax_(m, (unsigned)__shfl_xor((int)m, 1, 64));
            m = umax_(m, (unsigned)__shfl_xor((int)m, 2, 64));
            float thr = __uint_as_float(m) - WIN;
            float bk = -3.4e38f;
            int   bi = KCODES - 1;
            const float4* rv = (const float4*)&res[row][0];
            for (int k = 0; k < 16; ++k) {
                unsigned e = cp[k];
                if (__uint_as_float(e) >= thr) {
                    int idx = (int)(e & 0xFFFu);
                    const float4* cv = (const float4*)(cb + ((size_t)q * KCODES + idx) * DIMS);
                    float acc = 0.f;
#pragma unroll
                    for (int jj = 0; jj < 32; ++jj) {
                        float4 c4 = cv[jj];
                        float4 r4 = rv[jj];
                        acc = fmaf(r4.x, c4.x, acc);
                        acc = fmaf(r4.y, c4.y, acc);
                        acc = fmaf(r4.z, c4.z, acc);
                        acc = fmaf(r4.w, c4.w, acc);
                    }
                    float key = acc - 0.5f * csqq[idx];
                    if (key > bk || (key == bk && idx < bi)) { bk = key; bi = idx; }
                }
            }
#pragma unroll
            for (int mask = 1; mask <= 2; mask <<= 1) {
                float ok = __shfl_xor(bk, mask, 64);
                int   oi = __shfl_xor(bi, mask, 64);
                if (ok > bk || (ok == bk && oi < bi)) { bk = ok; bi = oi; }
            }
            if (s == 0) {
                fbin[row] = (float)bi;
                out[OUT_ELEMS + (size_t)(r0 + row) * NQ + q] = (float)bi;
            }
        }
        __syncthreads();

        // residual update + commitment loss; contiguous 32-float chunk/thread
        {
            int row = tid >> 2, j = tid & 3;
            int bi = (int)fbin[row];
            if (bi >= KCODES) bi = KCODES - 1;   // OOB guard (inert when winner exists)
            const float* cv = cb + ((size_t)q * KCODES + bi) * DIMS + j * 32;
            float* rp = &res[row][j * 32];
#pragma unroll
            for (int t = 0; t < 8; ++t) {
                float4 c4 = *(const float4*)(cv + t * 4);
                float4 r4 = *(const float4*)(rp + t * 4);
                r4.x -= c4.x; lossacc = fmaf(r4.x, r4.x, lossacc);
                r4.y -= c4.y; lossacc = fmaf(r4.y, r4.y, lossacc);
                r4.z -= c4.z; lossacc = fmaf(r4.z, r4.z, lossacc);
                r4.w -= c4.w; lossacc = fmaf(r4.w, r4.w, lossacc);
                *(float4*)(rp + t * 4) = r4;
            }
        }
    }

    // loss reduction
    __syncthreads();
    red[tid] = lossacc;
    __syncthreads();
    for (int s = 128; s > 0; s >>= 1) {
        if (tid < s) red[tid] += red[tid + s];
        __syncthreads();
    }
    if (tid == 0) atomicAdd(loss_accum, red[0]);

    // quantized output: out = x - final_residual
    {
        int d = tid >> 1, half = (tid & 1) * 32;
        const float* src = xb + (size_t)d * SEQ + half;
        float* dst = out + (size_t)b * DIMS * SEQ + (size_t)d * SEQ + n0 + half;
#pragma unroll
        for (int t4 = 0; t4 < 8; ++t4) {
            float4 v = *(const float4*)(src + t4 * 4);
            v.x -= res[half + t4 * 4 + 0][d];
            v.y -= res[half + t4 * 4 + 1][d];
            v.z -= res[half + t4 * 4 + 2][d];
            v.w -= res[half + t4 * 4 + 3][d];
            *(float4*)(dst + t4 * 4) = v;
        }
    }
}

__global__ void finish_loss(const float* __restrict__ loss_accum, float* __restrict__ out) {
    out[OUT_ELEMS + IDX_ELEMS] = loss_accum[0] * LOSS_DIV;
}

extern "C" void kernel_launch(void* const* d_in, const int* in_sizes, int n_in,
                              void* d_out, int out_size, void* d_ws, size_t ws_size,
                              hipStream_t stream) {
    const float* x  = (const float*)d_in[0];
    const float* cb = (const float*)d_in[1];
    float* out = (float*)d_out;
    char*  ws  = (char*)d_ws;

    float*     loss_accum = (float*)ws;
    float*     csq     = (float*)(ws + 256);                       // 131072 B
    _Float16*  cinit_h = (_Float16*)(ws + 256 + 131072);           // 65536 B
    _Float16*  bhi     = (_Float16*)(ws + 256 + 131072 + 65536);   // 8 MB (+16KB
                                 // tail pad: last-q prefetch overreach lands here)

    hipLaunchKernelGGL(prep_csq,   dim3(128),  dim3(256), 0, stream, cb, csq, cinit_h);
    hipLaunchKernelGGL(prep_frags, dim3(2048), dim3(256), 0, stream, cb, bhi, loss_accum);
    hipLaunchKernelGGL(rvq_main,   dim3(NBLK), dim3(256), 0, stream,
                       x, cb, bhi, csq, cinit_h, out, loss_accum);
    hipLaunchKernelGGL(finish_loss, dim3(1), dim3(1), 0, stream, loss_accum, out);
}